// Round 3
// baseline (819.282 us; speedup 1.0000x reference)
//
#include <hip/hip_runtime.h>
#include <stdint.h>

#define M_ROWS 8192
#define K_DIM  4096
#define N_DIM  11008
#define KSTEPS (K_DIM / 64)      // 64 K-tiles of BK=64

// ---- 256x256 8-phase geometry ----
#define BM 256
#define BN 256
#define MBLKS (M_ROWS / BM)      // 32
#define NBLKS (N_DIM / BN)       // 43
#define NWG   (MBLKS * NBLKS)    // 1376  (%8 == 0 -> simple XCD swizzle bijective)

typedef __attribute__((ext_vector_type(4))) float          f32x4;
typedef __attribute__((ext_vector_type(8))) __bf16         bf16x8;
typedef __attribute__((ext_vector_type(4))) int            i32x4;
typedef __attribute__((ext_vector_type(8))) unsigned short u16x8;

__constant__ float NF4_TBL[16] = {
    -1.0f, -0.6961928009986877f, -0.5250730514526367f, -0.39491748809814453f,
    -0.28444138169288635f, -0.18477343022823334f, -0.10644006729125977f,
    -0.029167551919817924f, 0.0f, 0.07958029955625534f, 0.16093020141124725f,
    0.24611230194568634f, 0.33791524171829224f, 0.44070982933044434f,
    0.5626170039176941f, 0.7229568362236023f};

__device__ __forceinline__ unsigned short f2bf(float f) {
  uint32_t u = __float_as_uint(f);
  u += 0x7fffu + ((u >> 16) & 1u);   // RNE
  return (unsigned short)(u >> 16);
}

__device__ __forceinline__ void gload_lds16(const void* g, const void* l) {
  __builtin_amdgcn_global_load_lds(
      (const __attribute__((address_space(1))) void*)(uintptr_t)g,
      (__attribute__((address_space(3))) void*)(uint32_t)(uintptr_t)l,
      16, 0, 0);
}

// ---------------- prep 1: x fp32 -> bf16 ----------------
__global__ void convert_x_kernel(const float* __restrict__ x,
                                 unsigned short* __restrict__ xb) {
  const long n8 = (long)M_ROWS * K_DIM / 8;
  for (long t = (long)blockIdx.x * blockDim.x + threadIdx.x; t < n8;
       t += (long)gridDim.x * blockDim.x) {
    const float* p = x + t * 8;
    f32x4 v0 = *(const f32x4*)p;
    f32x4 v1 = *(const f32x4*)(p + 4);
    u16x8 o;
    o[0] = f2bf(v0[0]); o[1] = f2bf(v0[1]); o[2] = f2bf(v0[2]); o[3] = f2bf(v0[3]);
    o[4] = f2bf(v1[0]); o[5] = f2bf(v1[1]); o[6] = f2bf(v1[2]); o[7] = f2bf(v1[3]);
    *(u16x8*)(xb + t * 8) = o;
  }
}

// ---------------- prep 2: NF4 dequant W -> bf16 ----------------
__global__ void dequant_w_kernel(const int* __restrict__ qw,
                                 const int* __restrict__ qs,
                                 const float* __restrict__ qf,
                                 const float* __restrict__ mean,
                                 unsigned short* __restrict__ wb) {
  __shared__ float tbl[16];
  if (threadIdx.x < 16) tbl[threadIdx.x] = NF4_TBL[threadIdx.x];
  __syncthreads();
  const float mu = mean[0];
  const long n8 = (long)N_DIM * K_DIM / 8;
  for (long t = (long)blockIdx.x * blockDim.x + threadIdx.x; t < n8;
       t += (long)gridDim.x * blockDim.x) {
    long f = t * 8;
    int  g = (int)(f >> 6);
    float s = (float)qs[g] / qf[g >> 8] + mu;
    i32x4 q0 = *(const i32x4*)(qw + f);
    i32x4 q1 = *(const i32x4*)(qw + f + 4);
    u16x8 o;
    o[0] = f2bf(tbl[q0[0]] * s); o[1] = f2bf(tbl[q0[1]] * s);
    o[2] = f2bf(tbl[q0[2]] * s); o[3] = f2bf(tbl[q0[3]] * s);
    o[4] = f2bf(tbl[q1[0]] * s); o[5] = f2bf(tbl[q1[1]] * s);
    o[6] = f2bf(tbl[q1[2]] * s); o[7] = f2bf(tbl[q1[3]] * s);
    *(u16x8*)(wb + f) = o;
  }
}

// ---------------- 256x256 8-phase bf16 GEMM:  C = A[M,K] * B[N,K]^T ----------------
// 8 waves (2M x 4N), per-wave output 128x64. LDS 160 KiB:
//   A: double buffer  [2][256][64]  at 0      (parity t&1, 32 KB each)
//   B: TRIPLE buffer  [3][256][64]  at 65536  (slot t%3,  32 KB each)
// Stage plan (all via global_load_lds, linear dest, inverse-swizzled source):
//   tile t: p0 B(t+2)h0 -> slot (t+2)%3   p1 B(t+2)h1
//           p2 A(t+2)h0 -> parity t&1     p3 A(t+2)h1
// Ledger: A(t) reads all issue p0/p1 and complete by p1's lgkmcnt(0), so p2/p3
// stages into the same parity buffer are safe (barrier-ordered). B slot (t+2)%3
// was last read at tile t-1 -> no overlap. At each tile end ONE counted
// s_waitcnt vmcnt(8): the 8 loads of tile t (B/A for t+2) may stay in flight,
// everything older (B(t+1), A(t+1)) must have landed. B prefetch slack ~1.75
// tiles (~1100cy) > HBM-miss latency (~900cy); A slack ~1.5 tiles.
// T2 swizzle: ds_read at kb ^ ((row&7)<<4); global source chunk (lane&7)^(lane>>3).
#define STG(GP, LB)                                                              \
  gload_lds16((GP) + (long)srow * K_DIM + scol, &LDSbuf[(LB) + wid * 1024]);     \
  gload_lds16((GP) + (long)(64 + srow) * K_DIM + scol,                           \
              &LDSbuf[(LB) + 8192 + wid * 1024]);

__global__ __launch_bounds__(512, 2) void gemm_8phase(
    const unsigned short* __restrict__ xb, const unsigned short* __restrict__ wb,
    float* __restrict__ C) {
  __align__(16) __shared__ unsigned char LDSbuf[163840];   // full 160 KiB/CU

  const int tid = threadIdx.x;
  const int wid = tid >> 6, lane = tid & 63;
  const int wr = wid >> 2, wc = wid & 3;
  const int r16 = lane & 15, hi = lane >> 4;

  // XCD-aware bijective swizzle (NWG % 8 == 0)
  const int wg = ((int)blockIdx.x & 7) * (NWG / 8) + ((int)blockIdx.x >> 3);
  const int mb = wg % MBLKS, nb = wg / MBLKS;
  const long m0g = (long)mb * BM, n0g = (long)nb * BN;

  // staging coords (per lane)
  const int srow = wid * 8 + (lane >> 3);
  const int scol = ((lane & 7) ^ (lane >> 3)) * 8;   // inverse-swizzled source chunk

  // ds_read coords
  const int aoff = (wr * 128 + r16) * 128;           // + m*2048 (+ parity*32768)
  const int boff = (wc * 64 + r16) * 128;            // + n*2048 (+ 65536 + slot*32768)
  const int kswz0 = ((hi ^ (r16 & 7)) << 4);
  const int kswz1 = kswz0 ^ 64;

  // ---- prologue: A(0),B(0) first (must land), then A(1),B(1) (may fly) ----
  STG(xb + m0g * K_DIM,               0);              // A(0) h0
  STG(xb + (m0g + 128) * K_DIM,       16384);          // A(0) h1
  STG(wb + n0g * K_DIM,               65536);          // B(0) h0 -> slot 0
  STG(wb + (n0g + 128) * K_DIM,       65536 + 16384);  // B(0) h1
  STG(xb + m0g * K_DIM + 64,          32768);          // A(1) h0 -> parity 1
  STG(xb + (m0g + 128) * K_DIM + 64,  32768 + 16384);  // A(1) h1
  STG(wb + n0g * K_DIM + 64,          65536 + 32768);  // B(1) h0 -> slot 1
  STG(wb + (n0g + 128) * K_DIM + 64,  65536 + 32768 + 16384);  // B(1) h1
  asm volatile("s_waitcnt vmcnt(8)");   // A(0),B(0) landed; A(1),B(1) in flight
  __builtin_amdgcn_sched_barrier(0);
  __builtin_amdgcn_s_barrier();

  bf16x8 af[8][2], bq[2][2];
  f32x4 acc[8][4] = {};

  int csB = 0;   // t % 3
  int ssB = 2;   // (t+2) % 3

  for (int t = 0; t < KSTEPS; ++t) {
    const int cur = t & 1;
    const int cA = cur * 32768;
    const int cB = 65536 + csB * 32768;
    const int sB = 65536 + ssB * 32768;
    const long kN = (long)((t + 2 < KSTEPS ? t + 2 : KSTEPS - 1) * 64);

    // ---------- phase 0: read A m0-3 + B n0-1 ; stage B(t+2)h0 ----------
#pragma unroll
    for (int m = 0; m < 4; ++m) {
      af[m][0] = *(const bf16x8*)&LDSbuf[cA + aoff + m * 2048 + kswz0];
      af[m][1] = *(const bf16x8*)&LDSbuf[cA + aoff + m * 2048 + kswz1];
    }
#pragma unroll
    for (int n = 0; n < 2; ++n) {
      bq[n][0] = *(const bf16x8*)&LDSbuf[cB + boff + n * 2048 + kswz0];
      bq[n][1] = *(const bf16x8*)&LDSbuf[cB + boff + n * 2048 + kswz1];
    }
    STG(wb + n0g * K_DIM + kN, sB);
    __builtin_amdgcn_s_barrier();
    asm volatile("s_waitcnt lgkmcnt(0)");
    __builtin_amdgcn_sched_barrier(0);
    __builtin_amdgcn_s_setprio(1);
#pragma unroll
    for (int m = 0; m < 4; ++m)
#pragma unroll
      for (int n = 0; n < 2; ++n) {
        acc[m][n] = __builtin_amdgcn_mfma_f32_16x16x32_bf16(af[m][0], bq[n][0], acc[m][n], 0, 0, 0);
        acc[m][n] = __builtin_amdgcn_mfma_f32_16x16x32_bf16(af[m][1], bq[n][1], acc[m][n], 0, 0, 0);
      }
    __builtin_amdgcn_s_setprio(0);
    __builtin_amdgcn_s_barrier();
    __builtin_amdgcn_sched_barrier(0);

    // ---------- phase 1: read A m4-7 ; stage B(t+2)h1 ----------
#pragma unroll
    for (int m = 4; m < 8; ++m) {
      af[m][0] = *(const bf16x8*)&LDSbuf[cA + aoff + m * 2048 + kswz0];
      af[m][1] = *(const bf16x8*)&LDSbuf[cA + aoff + m * 2048 + kswz1];
    }
    STG(wb + (n0g + 128) * K_DIM + kN, sB + 16384);
    __builtin_amdgcn_s_barrier();
    asm volatile("s_waitcnt lgkmcnt(0)");
    __builtin_amdgcn_sched_barrier(0);
    __builtin_amdgcn_s_setprio(1);
#pragma unroll
    for (int m = 4; m < 8; ++m)
#pragma unroll
      for (int n = 0; n < 2; ++n) {
        acc[m][n] = __builtin_amdgcn_mfma_f32_16x16x32_bf16(af[m][0], bq[n][0], acc[m][n], 0, 0, 0);
        acc[m][n] = __builtin_amdgcn_mfma_f32_16x16x32_bf16(af[m][1], bq[n][1], acc[m][n], 0, 0, 0);
      }
    __builtin_amdgcn_s_setprio(0);
    __builtin_amdgcn_s_barrier();
    __builtin_amdgcn_sched_barrier(0);

    // ---------- phase 2: read B n2-3 (A m0-3 in regs) ; stage A(t+2)h0 ----------
#pragma unroll
    for (int n = 0; n < 2; ++n) {
      bq[n][0] = *(const bf16x8*)&LDSbuf[cB + boff + (2 + n) * 2048 + kswz0];
      bq[n][1] = *(const bf16x8*)&LDSbuf[cB + boff + (2 + n) * 2048 + kswz1];
    }
    STG(xb + m0g * K_DIM + kN, cA);
    __builtin_amdgcn_s_barrier();
    asm volatile("s_waitcnt lgkmcnt(0)");
    __builtin_amdgcn_sched_barrier(0);
    __builtin_amdgcn_s_setprio(1);
#pragma unroll
    for (int m = 0; m < 4; ++m)
#pragma unroll
      for (int n = 0; n < 2; ++n) {
        acc[m][2 + n] = __builtin_amdgcn_mfma_f32_16x16x32_bf16(af[m][0], bq[n][0], acc[m][2 + n], 0, 0, 0);
        acc[m][2 + n] = __builtin_amdgcn_mfma_f32_16x16x32_bf16(af[m][1], bq[n][1], acc[m][2 + n], 0, 0, 0);
      }
    __builtin_amdgcn_s_setprio(0);
    __builtin_amdgcn_s_barrier();
    __builtin_amdgcn_sched_barrier(0);

    // ---------- phase 3: A m4-7 x B n2-3 (all regs) ; stage A(t+2)h1 ----------
    STG(xb + (m0g + 128) * K_DIM + kN, cA + 16384);
    __builtin_amdgcn_s_barrier();
    asm volatile("s_waitcnt lgkmcnt(0)");
    __builtin_amdgcn_sched_barrier(0);
    __builtin_amdgcn_s_setprio(1);
#pragma unroll
    for (int m = 4; m < 8; ++m)
#pragma unroll
      for (int n = 0; n < 2; ++n) {
        acc[m][2 + n] = __builtin_amdgcn_mfma_f32_16x16x32_bf16(af[m][0], bq[n][0], acc[m][2 + n], 0, 0, 0);
        acc[m][2 + n] = __builtin_amdgcn_mfma_f32_16x16x32_bf16(af[m][1], bq[n][1], acc[m][2 + n], 0, 0, 0);
      }
    __builtin_amdgcn_s_setprio(0);
    asm volatile("s_waitcnt vmcnt(8)");   // counted: only tile t's 8 stages may remain
    __builtin_amdgcn_sched_barrier(0);
    __builtin_amdgcn_s_barrier();
    __builtin_amdgcn_sched_barrier(0);

    csB = (csB == 2) ? 0 : csB + 1;
    ssB = (ssB == 2) ? 0 : ssB + 1;
  }

  // ---- epilogue: C/D layout col=lane&15, row=hi*4+reg; nontemporal ----
  const long crow = m0g + wr * 128 + hi * 4;
  const long ccol = n0g + wc * 64 + r16;
#pragma unroll
  for (int m = 0; m < 8; ++m)
#pragma unroll
    for (int n = 0; n < 4; ++n)
#pragma unroll
      for (int r = 0; r < 4; ++r)
        __builtin_nontemporal_store(
            acc[m][n][r], &C[(crow + m * 16 + r) * N_DIM + ccol + n * 16]);
}

// ---------------- fallback (no workspace): fused 128^2 kernel ----------------
__global__ __launch_bounds__(256) void gemm_fallback(
    const float* __restrict__ Xf, const int* __restrict__ qw,
    const int* __restrict__ qs, const float* __restrict__ qf,
    const float* __restrict__ meanp, float* __restrict__ C) {
  __shared__ unsigned short As[128 * 64];
  __shared__ unsigned short Bs[128 * 64];
  __shared__ float tbl[16];
  const int tid = threadIdx.x;
  if (tid < 16) tbl[tid] = NF4_TBL[tid];
  const float mu = meanp[0];
  const int nwg = (M_ROWS / 128) * (N_DIM / 128);
  const int wg = ((int)blockIdx.x & 7) * (nwg / 8) + ((int)blockIdx.x >> 3);
  const int mb = wg % (M_ROWS / 128), nb = wg / (M_ROWS / 128);
  const int m0 = mb * 128, n0 = nb * 128;
  const int wid = tid >> 6, lane = tid & 63;
  const int wr = wid >> 1, wcc = wid & 1;
  const int r16 = lane & 15, hi = lane >> 4;
  f32x4 acc[4][4] = {};
  for (int t = 0; t < KSTEPS; ++t) {
    const int k0 = t * 64;
    __syncthreads();
#pragma unroll
    for (int i = 0; i < 4; ++i) {
      int gi = i * 256 + tid;
      int row = gi >> 3, kq = (gi & 7) * 8;
      const float* px = Xf + (long)(m0 + row) * K_DIM + k0 + kq;
      f32x4 v0 = *(const f32x4*)px;
      f32x4 v1 = *(const f32x4*)(px + 4);
      u16x8 o;
      o[0] = f2bf(v0[0]); o[1] = f2bf(v0[1]); o[2] = f2bf(v0[2]); o[3] = f2bf(v0[3]);
      o[4] = f2bf(v1[0]); o[5] = f2bf(v1[1]); o[6] = f2bf(v1[2]); o[7] = f2bf(v1[3]);
      *(u16x8*)&As[row * 64 + kq] = o;
    }
#pragma unroll
    for (int i = 0; i < 4; ++i) {
      int gi = i * 256 + tid;
      int row = gi >> 3, kq = (gi & 7) * 8;
      const int* pq = qw + (long)(n0 + row) * K_DIM + k0 + kq;
      i32x4 q0 = *(const i32x4*)pq;
      i32x4 q1 = *(const i32x4*)(pq + 4);
      int g = (n0 + row) * (K_DIM / 64) + t;
      float s = (float)qs[g] / qf[g >> 8] + mu;
      u16x8 o;
      o[0] = f2bf(tbl[q0[0]] * s); o[1] = f2bf(tbl[q0[1]] * s);
      o[2] = f2bf(tbl[q0[2]] * s); o[3] = f2bf(tbl[q0[3]] * s);
      o[4] = f2bf(tbl[q1[0]] * s); o[5] = f2bf(tbl[q1[1]] * s);
      o[6] = f2bf(tbl[q1[2]] * s); o[7] = f2bf(tbl[q1[3]] * s);
      *(u16x8*)&Bs[row * 64 + kq] = o;
    }
    __syncthreads();
    bf16x8 afr[4][2], bfr[4][2];
#pragma unroll
    for (int i = 0; i < 4; ++i)
#pragma unroll
      for (int h = 0; h < 2; ++h) {
        afr[i][h] = *(const bf16x8*)&As[(wr * 64 + i * 16 + r16) * 64 + h * 32 + hi * 8];
        bfr[i][h] = *(const bf16x8*)&Bs[(wcc * 64 + i * 16 + r16) * 64 + h * 32 + hi * 8];
      }
#pragma unroll
    for (int i = 0; i < 4; ++i)
#pragma unroll
      for (int j = 0; j < 4; ++j) {
        acc[i][j] = __builtin_amdgcn_mfma_f32_16x16x32_bf16(afr[i][0], bfr[j][0], acc[i][j], 0, 0, 0);
        acc[i][j] = __builtin_amdgcn_mfma_f32_16x16x32_bf16(afr[i][1], bfr[j][1], acc[i][j], 0, 0, 0);
      }
  }
  const int crow = m0 + wr * 64 + hi * 4;
  const int ccol = n0 + wcc * 64 + r16;
#pragma unroll
  for (int i = 0; i < 4; ++i)
#pragma unroll
    for (int j = 0; j < 4; ++j)
#pragma unroll
      for (int r = 0; r < 4; ++r)
        C[(long)(crow + i * 16 + r) * N_DIM + (ccol + j * 16)] = acc[i][j][r];
}

extern "C" void kernel_launch(void* const* d_in, const int* in_sizes, int n_in,
                              void* d_out, int out_size, void* d_ws, size_t ws_size,
                              hipStream_t stream) {
  const float* x    = (const float*)d_in[0];
  const int*   qw   = (const int*)d_in[1];
  const int*   qs   = (const int*)d_in[2];
  const float* qf   = (const float*)d_in[3];
  const float* mean = (const float*)d_in[4];
  float* out = (float*)d_out;

  const size_t xb_bytes = (size_t)M_ROWS * K_DIM * 2;  // 64 MiB
  const size_t wb_bytes = (size_t)N_DIM * K_DIM * 2;   // 86 MiB

  if (ws_size >= xb_bytes + wb_bytes) {
    unsigned short* xb = (unsigned short*)d_ws;
    unsigned short* wb = (unsigned short*)((char*)d_ws + xb_bytes);
    convert_x_kernel<<<4096, 256, 0, stream>>>(x, xb);
    dequant_w_kernel<<<4096, 256, 0, stream>>>(qw, qs, qf, mean, wb);
    gemm_8phase<<<NWG, 512, 0, stream>>>(xb, wb, out);
  } else {
    gemm_fallback<<<(M_ROWS / 128) * (N_DIM / 128), 256, 0, stream>>>(
        x, qw, qs, qf, mean, out);
  }
}

// Round 4
// 797.956 us; speedup vs baseline: 1.0267x; 1.0267x over previous
//
#include <hip/hip_runtime.h>
#include <stdint.h>

#define M_ROWS 8192
#define K_DIM  4096
#define N_DIM  11008
#define KSTEPS (K_DIM / 64)      // 64 K-tiles of BK=64

// ---- 256x256 8-phase geometry ----
#define BM 256
#define BN 256
#define MBLKS (M_ROWS / BM)      // 32
#define NBLKS (N_DIM / BN)      // 43
#define NWG   (MBLKS * NBLKS)    // 1376  (%8 == 0 -> simple XCD swizzle bijective)

typedef __attribute__((ext_vector_type(4))) float          f32x4;
typedef __attribute__((ext_vector_type(8))) __bf16         bf16x8;
typedef __attribute__((ext_vector_type(4))) int            i32x4;
typedef __attribute__((ext_vector_type(8))) unsigned short u16x8;

__constant__ float NF4_TBL[16] = {
    -1.0f, -0.6961928009986877f, -0.5250730514526367f, -0.39491748809814453f,
    -0.28444138169288635f, -0.18477343022823334f, -0.10644006729125977f,
    -0.029167551919817924f, 0.0f, 0.07958029955625534f, 0.16093020141124725f,
    0.24611230194568634f, 0.33791524171829224f, 0.44070982933044434f,
    0.5626170039176941f, 0.7229568362236023f};

__device__ __forceinline__ unsigned short f2bf(float f) {
  uint32_t u = __float_as_uint(f);
  u += 0x7fffu + ((u >> 16) & 1u);   // RNE
  return (unsigned short)(u >> 16);
}

__device__ __forceinline__ void gload_lds16(const void* g, const void* l) {
  __builtin_amdgcn_global_load_lds(
      (const __attribute__((address_space(1))) void*)(uintptr_t)g,
      (__attribute__((address_space(3))) void*)(uint32_t)(uintptr_t)l,
      16, 0, 0);
}

// ---------------- prep 1: x fp32 -> bf16 ----------------
__global__ void convert_x_kernel(const float* __restrict__ x,
                                 unsigned short* __restrict__ xb) {
  const long n8 = (long)M_ROWS * K_DIM / 8;
  for (long t = (long)blockIdx.x * blockDim.x + threadIdx.x; t < n8;
       t += (long)gridDim.x * blockDim.x) {
    const float* p = x + t * 8;
    f32x4 v0 = *(const f32x4*)p;
    f32x4 v1 = *(const f32x4*)(p + 4);
    u16x8 o;
    o[0] = f2bf(v0[0]); o[1] = f2bf(v0[1]); o[2] = f2bf(v0[2]); o[3] = f2bf(v0[3]);
    o[4] = f2bf(v1[0]); o[5] = f2bf(v1[1]); o[6] = f2bf(v1[2]); o[7] = f2bf(v1[3]);
    *(u16x8*)(xb + t * 8) = o;
  }
}

// ---------------- prep 2: NF4 dequant W -> bf16 ----------------
__global__ void dequant_w_kernel(const int* __restrict__ qw,
                                 const int* __restrict__ qs,
                                 const float* __restrict__ qf,
                                 const float* __restrict__ mean,
                                 unsigned short* __restrict__ wb) {
  __shared__ float tbl[16];
  if (threadIdx.x < 16) tbl[threadIdx.x] = NF4_TBL[threadIdx.x];
  __syncthreads();
  const float mu = mean[0];
  const long n8 = (long)N_DIM * K_DIM / 8;
  for (long t = (long)blockIdx.x * blockDim.x + threadIdx.x; t < n8;
       t += (long)gridDim.x * blockDim.x) {
    long f = t * 8;
    int  g = (int)(f >> 6);
    float s = (float)qs[g] / qf[g >> 8] + mu;
    i32x4 q0 = *(const i32x4*)(qw + f);
    i32x4 q1 = *(const i32x4*)(qw + f + 4);
    u16x8 o;
    o[0] = f2bf(tbl[q0[0]] * s); o[1] = f2bf(tbl[q0[1]] * s);
    o[2] = f2bf(tbl[q0[2]] * s); o[3] = f2bf(tbl[q0[3]] * s);
    o[4] = f2bf(tbl[q1[0]] * s); o[5] = f2bf(tbl[q1[1]] * s);
    o[6] = f2bf(tbl[q1[2]] * s); o[7] = f2bf(tbl[q1[3]] * s);
    *(u16x8*)(wb + f) = o;
  }
}

// ---------------- 256x256 8-phase bf16 GEMM:  C = A[M,K] * B[N,K]^T ----------------
// Round-2 proven ledger (double-buffer, vmcnt(4)) with RELAXED per-phase waits:
// no explicit lgkmcnt(0) drains -- every ds_read is consumed by an MFMA in the
// same phase, so the compiler emits progressive lgkmcnt(N) waits inside the
// cluster (m97 mechanism). Cross-wave A-clobber safety: sched_barrier(0)
// immediately before each phase-ending s_barrier pins reads+MFMAs above the
// barrier; MFMA execution implies its ds_reads returned, so all waves' A(t)
// reads are complete before any wave passes the barrier that precedes the
// p2/p3 stages into the same A parity region. Tile boundary keeps
// vmcnt(4)+sched_barrier+s_barrier (prevents next-tile reads hoisting over
// the buffer flip).
#define STG(GP, LB)                                                              \
  gload_lds16((GP) + (long)srow * K_DIM + scol, &LDSbuf[(LB) + wid * 1024]);     \
  gload_lds16((GP) + (long)(64 + srow) * K_DIM + scol,                           \
              &LDSbuf[(LB) + 8192 + wid * 1024]);

__global__ __launch_bounds__(512, 2) void gemm_8phase(
    const unsigned short* __restrict__ xb, const unsigned short* __restrict__ wb,
    float* __restrict__ C) {
  __align__(16) __shared__ unsigned char LDSbuf[131072];

  const int tid = threadIdx.x;
  const int wid = tid >> 6, lane = tid & 63;
  const int wr = wid >> 2, wc = wid & 3;
  const int r16 = lane & 15, hi = lane >> 4;

  // XCD-aware bijective swizzle (NWG % 8 == 0)
  const int wg = ((int)blockIdx.x & 7) * (NWG / 8) + ((int)blockIdx.x >> 3);
  const int mb = wg % MBLKS, nb = wg / MBLKS;
  const long m0g = (long)mb * BM, n0g = (long)nb * BN;

  // staging coords (per lane)
  const int srow = wid * 8 + (lane >> 3);
  const int scol = ((lane & 7) ^ (lane >> 3)) * 8;   // inverse-swizzled source chunk

  // ds_read coords
  const int aoff = (wr * 128 + r16) * 128;           // + m*2048 (+ parity*32768)
  const int boff = (wc * 64 + r16) * 128;            // + n*2048 (+ 65536 + parity*32768)
  const int kswz0 = ((hi ^ (r16 & 7)) << 4);
  const int kswz1 = kswz0 ^ 64;

  // ---- prologue: A(0)h0,h1  B(0)h0,h1  A(1)h0,h1 ; wait all but A(1) halves ----
  STG(xb + m0g * K_DIM,               0);
  STG(xb + (m0g + 128) * K_DIM,       16384);
  STG(wb + n0g * K_DIM,               65536);
  STG(wb + (n0g + 128) * K_DIM,       65536 + 16384);
  STG(xb + m0g * K_DIM + 64,          32768);
  STG(xb + (m0g + 128) * K_DIM + 64,  32768 + 16384);
  asm volatile("s_waitcnt vmcnt(4)");
  __builtin_amdgcn_sched_barrier(0);
  __builtin_amdgcn_s_barrier();

  bf16x8 af[8][2], bq[2][2];
  f32x4 acc[8][4] = {};

  for (int t = 0; t < KSTEPS; ++t) {
    const int cur = t & 1;
    const int cA = cur * 32768, cB = 65536 + cur * 32768;
    const int nB = 65536 + (cur ^ 1) * 32768;
    const long kB = (long)((t + 1 < KSTEPS ? t + 1 : KSTEPS - 1) * 64);
    const long kA = (long)((t + 2 < KSTEPS ? t + 2 : KSTEPS - 1) * 64);

    // ---------- phase 0: read A m0-3 + B n0-1 ; stage B(t+1)h0 ----------
#pragma unroll
    for (int m = 0; m < 4; ++m) {
      af[m][0] = *(const bf16x8*)&LDSbuf[cA + aoff + m * 2048 + kswz0];
      af[m][1] = *(const bf16x8*)&LDSbuf[cA + aoff + m * 2048 + kswz1];
    }
#pragma unroll
    for (int n = 0; n < 2; ++n) {
      bq[n][0] = *(const bf16x8*)&LDSbuf[cB + boff + n * 2048 + kswz0];
      bq[n][1] = *(const bf16x8*)&LDSbuf[cB + boff + n * 2048 + kswz1];
    }
    STG(wb + n0g * K_DIM + kB, nB);
    __builtin_amdgcn_s_barrier();
    __builtin_amdgcn_s_setprio(1);
#pragma unroll
    for (int m = 0; m < 4; ++m)
#pragma unroll
      for (int n = 0; n < 2; ++n) {
        acc[m][n] = __builtin_amdgcn_mfma_f32_16x16x32_bf16(af[m][0], bq[n][0], acc[m][n], 0, 0, 0);
        acc[m][n] = __builtin_amdgcn_mfma_f32_16x16x32_bf16(af[m][1], bq[n][1], acc[m][n], 0, 0, 0);
      }
    __builtin_amdgcn_s_setprio(0);
    __builtin_amdgcn_sched_barrier(0);
    __builtin_amdgcn_s_barrier();

    // ---------- phase 1: read A m4-7 ; stage B(t+1)h1 ----------
#pragma unroll
    for (int m = 4; m < 8; ++m) {
      af[m][0] = *(const bf16x8*)&LDSbuf[cA + aoff + m * 2048 + kswz0];
      af[m][1] = *(const bf16x8*)&LDSbuf[cA + aoff + m * 2048 + kswz1];
    }
    STG(wb + (n0g + 128) * K_DIM + kB, nB + 16384);
    __builtin_amdgcn_s_barrier();
    __builtin_amdgcn_s_setprio(1);
#pragma unroll
    for (int m = 4; m < 8; ++m)
#pragma unroll
      for (int n = 0; n < 2; ++n) {
        acc[m][n] = __builtin_amdgcn_mfma_f32_16x16x32_bf16(af[m][0], bq[n][0], acc[m][n], 0, 0, 0);
        acc[m][n] = __builtin_amdgcn_mfma_f32_16x16x32_bf16(af[m][1], bq[n][1], acc[m][n], 0, 0, 0);
      }
    __builtin_amdgcn_s_setprio(0);
    __builtin_amdgcn_sched_barrier(0);
    __builtin_amdgcn_s_barrier();

    // ---------- phase 2: read B n2-3 (A m0-3 in regs) ; stage A(t+2)h0 ----------
#pragma unroll
    for (int n = 0; n < 2; ++n) {
      bq[n][0] = *(const bf16x8*)&LDSbuf[cB + boff + (2 + n) * 2048 + kswz0];
      bq[n][1] = *(const bf16x8*)&LDSbuf[cB + boff + (2 + n) * 2048 + kswz1];
    }
    STG(xb + m0g * K_DIM + kA, cA);
    __builtin_amdgcn_s_barrier();
    __builtin_amdgcn_s_setprio(1);
#pragma unroll
    for (int m = 0; m < 4; ++m)
#pragma unroll
      for (int n = 0; n < 2; ++n) {
        acc[m][2 + n] = __builtin_amdgcn_mfma_f32_16x16x32_bf16(af[m][0], bq[n][0], acc[m][2 + n], 0, 0, 0);
        acc[m][2 + n] = __builtin_amdgcn_mfma_f32_16x16x32_bf16(af[m][1], bq[n][1], acc[m][2 + n], 0, 0, 0);
      }
    __builtin_amdgcn_s_setprio(0);
    __builtin_amdgcn_sched_barrier(0);
    __builtin_amdgcn_s_barrier();

    // ---------- phase 3: A m4-7 x B n2-3 (all regs) ; stage A(t+2)h1 ----------
    STG(xb + (m0g + 128) * K_DIM + kA, cA + 16384);
    __builtin_amdgcn_s_barrier();
    __builtin_amdgcn_s_setprio(1);
#pragma unroll
    for (int m = 4; m < 8; ++m)
#pragma unroll
      for (int n = 0; n < 2; ++n) {
        acc[m][2 + n] = __builtin_amdgcn_mfma_f32_16x16x32_bf16(af[m][0], bq[n][0], acc[m][2 + n], 0, 0, 0);
        acc[m][2 + n] = __builtin_amdgcn_mfma_f32_16x16x32_bf16(af[m][1], bq[n][1], acc[m][2 + n], 0, 0, 0);
      }
    __builtin_amdgcn_s_setprio(0);
    asm volatile("s_waitcnt vmcnt(4)");   // counted: only A(t+2) halves may remain in flight
    __builtin_amdgcn_sched_barrier(0);
    __builtin_amdgcn_s_barrier();
    __builtin_amdgcn_sched_barrier(0);
  }

  // ---- epilogue: C/D layout col=lane&15, row=hi*4+reg; nontemporal ----
  const long crow = m0g + wr * 128 + hi * 4;
  const long ccol = n0g + wc * 64 + r16;
#pragma unroll
  for (int m = 0; m < 8; ++m)
#pragma unroll
    for (int n = 0; n < 4; ++n)
#pragma unroll
      for (int r = 0; r < 4; ++r)
        __builtin_nontemporal_store(
            acc[m][n][r], &C[(crow + m * 16 + r) * N_DIM + ccol + n * 16]);
}

// ---------------- fallback (no workspace): fused 128^2 kernel ----------------
__global__ __launch_bounds__(256) void gemm_fallback(
    const float* __restrict__ Xf, const int* __restrict__ qw,
    const int* __restrict__ qs, const float* __restrict__ qf,
    const float* __restrict__ meanp, float* __restrict__ C) {
  __shared__ unsigned short As[128 * 64];
  __shared__ unsigned short Bs[128 * 64];
  __shared__ float tbl[16];
  const int tid = threadIdx.x;
  if (tid < 16) tbl[tid] = NF4_TBL[tid];
  const float mu = meanp[0];
  const int nwg = (M_ROWS / 128) * (N_DIM / 128);
  const int wg = ((int)blockIdx.x & 7) * (nwg / 8) + ((int)blockIdx.x >> 3);
  const int mb = wg % (M_ROWS / 128), nb = wg / (M_ROWS / 128);
  const int m0 = mb * 128, n0 = nb * 128;
  const int wid = tid >> 6, lane = tid & 63;
  const int wr = wid >> 1, wcc = wid & 1;
  const int r16 = lane & 15, hi = lane >> 4;
  f32x4 acc[4][4] = {};
  for (int t = 0; t < KSTEPS; ++t) {
    const int k0 = t * 64;
    __syncthreads();
#pragma unroll
    for (int i = 0; i < 4; ++i) {
      int gi = i * 256 + tid;
      int row = gi >> 3, kq = (gi & 7) * 8;
      const float* px = Xf + (long)(m0 + row) * K_DIM + k0 + kq;
      f32x4 v0 = *(const f32x4*)px;
      f32x4 v1 = *(const f32x4*)(px + 4);
      u16x8 o;
      o[0] = f2bf(v0[0]); o[1] = f2bf(v0[1]); o[2] = f2bf(v0[2]); o[3] = f2bf(v0[3]);
      o[4] = f2bf(v1[0]); o[5] = f2bf(v1[1]); o[6] = f2bf(v1[2]); o[7] = f2bf(v1[3]);
      *(u16x8*)&As[row * 64 + kq] = o;
    }
#pragma unroll
    for (int i = 0; i < 4; ++i) {
      int gi = i * 256 + tid;
      int row = gi >> 3, kq = (gi & 7) * 8;
      const int* pq = qw + (long)(n0 + row) * K_DIM + k0 + kq;
      i32x4 q0 = *(const i32x4*)pq;
      i32x4 q1 = *(const i32x4*)(pq + 4);
      int g = (n0 + row) * (K_DIM / 64) + t;
      float s = (float)qs[g] / qf[g >> 8] + mu;
      u16x8 o;
      o[0] = f2bf(tbl[q0[0]] * s); o[1] = f2bf(tbl[q0[1]] * s);
      o[2] = f2bf(tbl[q0[2]] * s); o[3] = f2bf(tbl[q0[3]] * s);
      o[4] = f2bf(tbl[q1[0]] * s); o[5] = f2bf(tbl[q1[1]] * s);
      o[6] = f2bf(tbl[q1[2]] * s); o[7] = f2bf(tbl[q1[3]] * s);
      *(u16x8*)&Bs[row * 64 + kq] = o;
    }
    __syncthreads();
    bf16x8 afr[4][2], bfr[4][2];
#pragma unroll
    for (int i = 0; i < 4; ++i)
#pragma unroll
      for (int h = 0; h < 2; ++h) {
        afr[i][h] = *(const bf16x8*)&As[(wr * 64 + i * 16 + r16) * 64 + h * 32 + hi * 8];
        bfr[i][h] = *(const bf16x8*)&Bs[(wcc * 64 + i * 16 + r16) * 64 + h * 32 + hi * 8];
      }
#pragma unroll
    for (int i = 0; i < 4; ++i)
#pragma unroll
      for (int j = 0; j < 4; ++j) {
        acc[i][j] = __builtin_amdgcn_mfma_f32_16x16x32_bf16(afr[i][0], bfr[j][0], acc[i][j], 0, 0, 0);
        acc[i][j] = __builtin_amdgcn_mfma_f32_16x16x32_bf16(afr[i][1], bfr[j][1], acc[i][j], 0, 0, 0);
      }
  }
  const int crow = m0 + wr * 64 + hi * 4;
  const int ccol = n0 + wcc * 64 + r16;
#pragma unroll
  for (int i = 0; i < 4; ++i)
#pragma unroll
    for (int j = 0; j < 4; ++j)
#pragma unroll
      for (int r = 0; r < 4; ++r)
        C[(long)(crow + i * 16 + r) * N_DIM + (ccol + j * 16)] = acc[i][j][r];
}

extern "C" void kernel_launch(void* const* d_in, const int* in_sizes, int n_in,
                              void* d_out, int out_size, void* d_ws, size_t ws_size,
                              hipStream_t stream) {
  const float* x    = (const float*)d_in[0];
  const int*   qw   = (const int*)d_in[1];
  const int*   qs   = (const int*)d_in[2];
  const float* qf   = (const float*)d_in[3];
  const float* mean = (const float*)d_in[4];
  float* out = (float*)d_out;

  const size_t xb_bytes = (size_t)M_ROWS * K_DIM * 2;  // 64 MiB
  const size_t wb_bytes = (size_t)N_DIM * K_DIM * 2;   // 86 MiB

  if (ws_size >= xb_bytes + wb_bytes) {
    unsigned short* xb = (unsigned short*)d_ws;
    unsigned short* wb = (unsigned short*)((char*)d_ws + xb_bytes);
    convert_x_kernel<<<4096, 256, 0, stream>>>(x, xb);
    dequant_w_kernel<<<4096, 256, 0, stream>>>(qw, qs, qf, mean, wb);
    gemm_8phase<<<NWG, 512, 0, stream>>>(xb, wb, out);
  } else {
    gemm_fallback<<<(M_ROWS / 128) * (N_DIM / 128), 256, 0, stream>>>(
        x, qw, qs, qf, mean, out);
  }
}